// Round 10
// baseline (2717.594 us; speedup 1.0000x reference)
//
#include <hip/hip_runtime.h>

#define TT 512
#define VV 64
#define RING 16   // ch0 ring; window-4 flag quantum, per-step ACKs (R8-proven protocol)

typedef _Float16 f16;
typedef f16 f16x8 __attribute__((ext_vector_type(8)));
typedef f16 f16x4 __attribute__((ext_vector_type(4)));
typedef float f32x4v __attribute__((ext_vector_type(4)));
typedef unsigned long long u64;
typedef unsigned u32;

// address_space(1): mailbox atomics lower to global_* (vmcnt-only), never flat_*
typedef __attribute__((address_space(1))) unsigned gu32;
typedef __attribute__((address_space(1))) unsigned long long gu64;

#define MFMA(A_,B_,C_) __builtin_amdgcn_mfma_f32_16x16x32_f16((A_),(B_),(C_),0,0,0)
#define AT_LD32(p)   __hip_atomic_load((gu32*)(void*)(p), __ATOMIC_RELAXED, __HIP_MEMORY_SCOPE_AGENT)
#define AT_ST32(p,v) __hip_atomic_store((gu32*)(void*)(p),(v), __ATOMIC_RELAXED, __HIP_MEMORY_SCOPE_AGENT)
#define AT_LD64(p)   __hip_atomic_load((gu64*)(void*)(p), __ATOMIC_RELAXED, __HIP_MEMORY_SCOPE_AGENT)
#define AT_ST64(p,v) __hip_atomic_store((gu64*)(void*)(p),(v), __ATOMIC_RELAXED, __HIP_MEMORY_SCOPE_AGENT)

__device__ __forceinline__ void barrier_lds(){ asm volatile("s_waitcnt lgkmcnt(0)\n\ts_barrier" ::: "memory"); }
__device__ __forceinline__ void wait_vm0(){ asm volatile("s_waitcnt vmcnt(0)" ::: "memory"); }
__device__ __forceinline__ float4 ld4(const float* p){ return *(const float4*)p; }

__device__ __forceinline__ f16x8 ldA8(const float* p){
  f16x8 a;
  #pragma unroll
  for (int j = 0; j < 8; ++j) a[j] = (f16)p[j];
  return a;
}

// element offset (in f16 units) of (k=d0..d0+3, col=b) inside a B-frag buffer
// layout: [kt][lane'][j], lane' = ((d&31)>>3)*16 + b, j = d&7
__device__ __forceinline__ int fragOff16(int d0, int b){
  const int kt = d0 >> 5, qq = (d0 >> 3) & 3, j0 = d0 & 7;
  return (kt*64 + qq*16 + b)*8 + j0;
}

__device__ __forceinline__ void fragW_lds(f16x8* buf, int d0, int b, const float* h4){
  f16x4 v;
  #pragma unroll
  for (int e = 0; e < 4; ++e) v[e] = (f16)h4[e];
  *(f16x4*)((f16*)buf + fragOff16(d0, b)) = v;
}

__device__ __forceinline__ void pubFrag(char* slot, int d0, int b, const float* h4){
  union { f16x4 v; u64 u; } uu;
  #pragma unroll
  for (int e = 0; e < 4; ++e) uu.v[e] = (f16)h4[e];
  AT_ST64((u64*)(slot + fragOff16(d0, b)*2), uu.u);
}

__device__ __forceinline__ f16x8 impFrag(const char* slot, int kt, int lane){
  union { u64 u[2]; f16x8 v; } vv;
  const u64* p = (const u64*)(slot + (kt*64 + lane)*16);
  vv.u[0] = AT_LD64((u64*)p);
  vv.u[1] = AT_LD64((u64*)(p + 1));
  return vv.v;
}

__device__ __forceinline__ void spin_ge(u32* f, u32 val){
  if ((threadIdx.x & 63) == 0){
    u32 g = 0;
    while (AT_LD32(f) < val && ++g < (1u << 20)) {}
  }
  asm volatile("" ::: "memory");
}

// Fused-acc gates (R8): C0 = r-gate sum, C1 = z-gate sum; n needs Ci2/Ch2 separate.
__device__ __forceinline__ void gates_upd2(const f32x4v& C0, const f32x4v& C1,
                                           const f32x4v& Ci2, const f32x4v& Ch2,
                                           const float* bR, const float* bZ,
                                           const float* bI, const float* bH,
                                           float* hp){
  #pragma unroll
  for (int e = 0; e < 4; ++e){
    float rr = 1.f/(1.f + __expf(-(C0[e] + bR[e])));
    float zz = 1.f/(1.f + __expf(-(C1[e] + bZ[e])));
    float nv = Ci2[e] + bI[e] + rr*(Ch2[e] + bH[e]);
    float nn = 1.f - 2.f/(1.f + __expf(2.f*nv));
    hp[e] = (1.f - zz)*nn + zz*hp[e];
  }
}

__global__ void k_init(u32* wsf){
  const int i = blockIdx.x*256 + threadIdx.x;
  if (i < 4096) AT_ST32(wsf + i, 0u);
}

// R10: ONE mailbox channel. blocks 0..31: L1 producer -> ch0 (waves 0-7 work,
// waves 8-15 barrier-match idle). blocks 32..63: merged consumer, 16 waves:
// waves 0-7 = L2 (ch0 import, Wih2 staged in LDS, Whh2 in regs), waves 8-15 =
// L3+head (all weights in regs; h2 handoff via LDS sB; head on sD, delayed 2).
// Phase schedule = R2-verified merged-consumer; ch0 protocol = R8-verbatim
// (window-4 flags + vm0 drain, per-step ACKs, gate ACK>=t-13 at t%4==0 t>=16,
// spin flag>=min(s+7,TT) at s%4==3, initial spin 8, ring 16).
__launch_bounds__(1024, 1)
__global__ void k_pipe(const float* __restrict__ x,   const float* __restrict__ dd,
                       const float* __restrict__ m1,
                       const float* __restrict__ h01, const float* __restrict__ h02,
                       const float* __restrict__ h03,
                       const float* __restrict__ Wih1, const float* __restrict__ Whh1,
                       const float* __restrict__ bih1, const float* __restrict__ bhh1,
                       const float* __restrict__ Wih2, const float* __restrict__ Whh2,
                       const float* __restrict__ bih2, const float* __restrict__ bhh2,
                       const float* __restrict__ Wih3, const float* __restrict__ Whh3,
                       const float* __restrict__ bih3, const float* __restrict__ bhh3,
                       const float* __restrict__ Wout, const float* __restrict__ bout,
                       const float* __restrict__ Wdx,  const float* __restrict__ bdx,
                       const float* __restrict__ Wdh,  const float* __restrict__ bdh,
                       float* __restrict__ y, u32* __restrict__ wsf, char* __restrict__ wsd)
{
  __shared__ char smem[131072];

  const int tid = threadIdx.x, wid = tid >> 6, lane = tid & 63;
  const int q = lane >> 4, r = lane & 15;
  const int blk = blockIdx.x, grp = blk & 31, b0 = grp << 4;

  u32* const fl0 = wsf + grp*16;
  u32* const ak0 = wsf + 1024 + grp*16;
  char* const ring0 = wsd + (size_t)grp*RING*4096;

  // ===================== producer blocks =====================
  if (blk < 32){
    if (wid >= 8){
      // barrier-matching idle waves (1 barrier/step + 1 per 4-step window)
      __syncthreads();
      for (int t = 0; t < TT; ++t){
        barrier_lds();
        if ((t & 3) == 3) barrier_lds();
      }
      return;
    }
    f16x8* const sW     = (f16x8*)smem;             // [8*12*64] Whh1 frags (96 KB)
    f16x8* const sFragP = (f16x8*)(smem + 98304);   // [2][256] h1 B-frags (8 KB)
    f16x8* const sX1    = (f16x8*)(smem + 106496);  // [2][128] x B-frags (4 KB)

    const int dG = wid*16 + 4*q;
    f16x8 Ai[3][2];
    #pragma unroll
    for (int g = 0; g < 3; ++g){
      const int mrow = (g*8 + wid)*16 + r;
      #pragma unroll
      for (int kt = 0; kt < 2; ++kt) Ai[g][kt] = ldA8(Wih1 + mrow*64 + kt*32 + q*8);
      #pragma unroll
      for (int kt = 0; kt < 4; ++kt)
        sW[(wid*12 + g*4 + kt)*64 + lane] = ldA8(Whh1 + mrow*128 + kt*32 + q*8);
    }
    float bR[4], bZ[4], bI[4], bH[4], hS[4], WdhL[4], bdhL[4];
    #pragma unroll
    for (int e = 0; e < 4; ++e){
      const int d = dG + e;
      bR[e] = bih1[d] + bhh1[d];
      bZ[e] = bih1[128+d] + bhh1[128+d];
      bI[e] = bih1[256+d];
      bH[e] = bhh1[256+d];
      WdhL[e] = Wdh[d]; bdhL[e] = bdh[d];
    }
    { float4 a = ld4(h01 + (size_t)(b0+r)*128 + dG); hS[0]=a.x; hS[1]=a.y; hS[2]=a.z; hS[3]=a.w; }
    float dhC = 0.f, dhN = dd[(size_t)(b0+r)*TT + 1];

    const int bx = (wid & 3)*4 + q, v0 = 4*r;
    float Wdx4[4] = {0,0,0,0}, bdx4[4] = {0,0,0,0};
    float4 xC = {0,0,0,0}, x0v = {0,0,0,0}, xN = {0,0,0,0}, mN = {0,0,0,0};
    float4 xP = {0,0,0,0}, mC = {0,0,0,0};
    float dxC = 0.f, dxN = 0.f;
    if (wid < 4){
      #pragma unroll
      for (int e = 0; e < 4; ++e){ Wdx4[e] = Wdx[v0+e]; bdx4[e] = bdx[v0+e]; }
      xC  = ld4(x + ((size_t)(b0+bx)*TT + 0)*VV + v0);
      x0v = xC;
      xN  = ld4(x  + ((size_t)(b0+bx)*TT + 1)*VV + v0);
      mN  = ld4(m1 + ((size_t)(b0+bx)*TT + 1)*VV + v0);
      dxN = dd[(size_t)(b0+bx)*TT + 1];
      xP = xC; mC = mN; dxC = dxN;
    }
    __syncthreads();

    for (int t = 0; t < TT; ++t){
      const int par = t & 1;
      if ((t & 3) == 0 && t >= 16) spin_ge(ak0, (u32)(t-13));
      if (wid < 4){
        float xi[4];
        if (t == 0){ xi[0]=xC.x; xi[1]=xC.y; xi[2]=xC.z; xi[3]=xC.w; }
        else {
          const float* xc = (const float*)&xC; const float* xp = (const float*)&xP;
          const float* x0e = (const float*)&x0v; const float* me = (const float*)&mC;
          #pragma unroll
          for (int e = 0; e < 4; ++e){
            float gx = __expf(-fmaxf(dxC*Wdx4[e] + bdx4[e], 0.f));
            xi[e] = (xp[e]*gx + (1.f-gx)*x0e[e])*(1.f-me[e]) + me[e]*xc[e];
          }
        }
        fragW_lds(sX1 + par*128, v0, bx, xi);
      }
      if (t >= 1){
        #pragma unroll
        for (int e = 0; e < 4; ++e)
          hS[e] *= __expf(-fmaxf(dhC*WdhL[e] + bdhL[e], 0.f));
      }
      fragW_lds(sFragP + par*256, dG, r, hS);
      barrier_lds();
      f16x8 bx1[2], bh4[4];
      #pragma unroll
      for (int kt = 0; kt < 2; ++kt) bx1[kt] = sX1[par*128 + kt*64 + lane];
      #pragma unroll
      for (int kt = 0; kt < 4; ++kt) bh4[kt] = sFragP[par*256 + kt*64 + lane];
      f32x4v C0 = {0,0,0,0}, C1 = {0,0,0,0}, Ci2 = {0,0,0,0}, Ch2 = {0,0,0,0};
      #pragma unroll
      for (int kt = 0; kt < 4; ++kt) C0  = MFMA(sW[(wid*12 + 0*4 + kt)*64 + lane], bh4[kt], C0);
      #pragma unroll
      for (int kt = 0; kt < 4; ++kt) C1  = MFMA(sW[(wid*12 + 1*4 + kt)*64 + lane], bh4[kt], C1);
      #pragma unroll
      for (int kt = 0; kt < 4; ++kt) Ch2 = MFMA(sW[(wid*12 + 2*4 + kt)*64 + lane], bh4[kt], Ch2);
      #pragma unroll
      for (int kt = 0; kt < 2; ++kt) C0  = MFMA(Ai[0][kt], bx1[kt], C0);
      #pragma unroll
      for (int kt = 0; kt < 2; ++kt) C1  = MFMA(Ai[1][kt], bx1[kt], C1);
      #pragma unroll
      for (int kt = 0; kt < 2; ++kt) Ci2 = MFMA(Ai[2][kt], bx1[kt], Ci2);
      gates_upd2(C0, C1, Ci2, Ch2, bR, bZ, bI, bH, hS);
      pubFrag(ring0 + (size_t)(t & (RING-1))*4096, dG, r, hS);
      if ((t & 3) == 3){
        wait_vm0();
        barrier_lds();
        if (tid == 0) AT_ST32(fl0, (u32)(t+1));
      }
      dhC = dhN;
      const int tp = (t+2 < TT) ? (t+2) : (TT-1);
      dhN = dd[(size_t)(b0+r)*TT + tp];
      if (wid < 4){
        xP = xC; xC = xN; mC = mN; dxC = dxN;
        xN  = ld4(x  + ((size_t)(b0+bx)*TT + tp)*VV + v0);
        mN  = ld4(m1 + ((size_t)(b0+bx)*TT + tp)*VV + v0);
        dxN = dd[(size_t)(b0+bx)*TT + tp];
      }
    }
    return;
  }

  // ===================== consumer blocks: merged L2 + L3/head =====================
  {
    f16x8* const sA  = (f16x8*)smem;            // [2][256] decayed h2 (L2's B-op)
    f16x8* const sB  = (f16x8*)(smem + 8192);   // [2][256] raw h2 (L3's x-input)
    f16x8* const sC  = (f16x8*)(smem + 16384);  // [2][256] decayed h3 (L3's B-op)
    f16x8* const sD  = (f16x8*)(smem + 24576);  // [2][256] raw h3 (head input)
    f16x8* const sW2 = (f16x8*)(smem + 32768);  // [8*12*64] Wih2 frags (96 KB)

    const int half = wid >> 3, w8 = wid & 7;
    const int dG = w8*16 + 4*q;

    const float* bihX = half ? bih3 : bih2;
    const float* bhhX = half ? bhh3 : bhh2;
    const float* h0X  = half ? h03  : h02;

    float bR[4], bZ[4], bI[4], bH[4], hS[4], WdhL[4], bdhL[4];
    #pragma unroll
    for (int e = 0; e < 4; ++e){
      const int d = dG + e;
      bR[e] = bihX[d] + bhhX[d];
      bZ[e] = bihX[128+d] + bhhX[128+d];
      bI[e] = bihX[256+d];
      bH[e] = bhhX[256+d];
      WdhL[e] = Wdh[d]; bdhL[e] = bdh[d];
    }
    { float4 a = ld4(h0X + (size_t)(b0+r)*128 + dG); hS[0]=a.x; hS[1]=a.y; hS[2]=a.z; hS[3]=a.w; }

    if (half == 0){
      // ---------------- L2 waves ----------------
      f16x8 Ah[3][4];
      #pragma unroll
      for (int g = 0; g < 3; ++g){
        const int mrow = (g*8 + w8)*16 + r;
        #pragma unroll
        for (int kt = 0; kt < 4; ++kt){
          sW2[(w8*12 + g*4 + kt)*64 + lane] = ldA8(Wih2 + mrow*128 + kt*32 + q*8);
          Ah[g][kt] = ldA8(Whh2 + mrow*128 + kt*32 + q*8);
        }
      }
      float dhC = 0.f, dhN = dd[(size_t)(b0+r)*TT + 1];
      __syncthreads();

      spin_ge(fl0, 8u);
      f16x8 bi[4];
      #pragma unroll
      for (int kt = 0; kt < 4; ++kt) bi[kt] = impFrag(ring0, kt, lane);

      for (int s = 0; s <= TT+1; ++s){
        const int par = s & 1;
        if (s <= TT) fragW_lds(sB + par*256, dG, r, hS);      // raw h2(s-1) for L3
        if (s >= 1 && s < TT){
          #pragma unroll
          for (int e = 0; e < 4; ++e)
            hS[e] *= __expf(-fmaxf(dhC*WdhL[e] + bdhL[e], 0.f));
        }
        if (s < TT) fragW_lds(sA + par*256, dG, r, hS);       // decayed (own B-op)
        barrier_lds();
        if (s < TT){
          if (tid == 0) AT_ST32(ak0, (u32)s);                 // steps <= s-1 consumed
          f16x8 bh4[4];
          #pragma unroll
          for (int kt = 0; kt < 4; ++kt) bh4[kt] = sA[par*256 + kt*64 + lane];
          f32x4v C0 = {0,0,0,0}, C1 = {0,0,0,0}, Ci2 = {0,0,0,0}, Ch2 = {0,0,0,0};
          #pragma unroll
          for (int kt = 0; kt < 4; ++kt) C0  = MFMA(Ah[0][kt], bh4[kt], C0);
          #pragma unroll
          for (int kt = 0; kt < 4; ++kt) C1  = MFMA(Ah[1][kt], bh4[kt], C1);
          #pragma unroll
          for (int kt = 0; kt < 4; ++kt) Ch2 = MFMA(Ah[2][kt], bh4[kt], Ch2);
          #pragma unroll
          for (int kt = 0; kt < 4; ++kt) C0  = MFMA(sW2[(w8*12 + 0*4 + kt)*64 + lane], bi[kt], C0);
          #pragma unroll
          for (int kt = 0; kt < 4; ++kt) C1  = MFMA(sW2[(w8*12 + 1*4 + kt)*64 + lane], bi[kt], C1);
          #pragma unroll
          for (int kt = 0; kt < 4; ++kt) Ci2 = MFMA(sW2[(w8*12 + 2*4 + kt)*64 + lane], bi[kt], Ci2);
          if (s + 1 < TT){
            const char* sIn = ring0 + (size_t)((s+1) & (RING-1))*4096;
            #pragma unroll
            for (int kt = 0; kt < 4; ++kt) bi[kt] = impFrag(sIn, kt, lane);
          }
          gates_upd2(C0, C1, Ci2, Ch2, bR, bZ, bI, bH, hS);   // hS = h2(s)
          if ((s & 3) == 3 && s < TT-1) spin_ge(fl0, (u32)(s+7 <= TT ? s+7 : TT));
        }
        dhC = dhN;
        const int tp = (s+2 < TT) ? (s+2) : (TT-1);
        dhN = dd[(size_t)(b0+r)*TT + tp];
      }
    } else {
      // ---------------- L3 + head waves ----------------
      f16x8 Ai3[3][4], Ah3[3][4];
      #pragma unroll
      for (int g = 0; g < 3; ++g){
        const int mrow = (g*8 + w8)*16 + r;
        #pragma unroll
        for (int kt = 0; kt < 4; ++kt){
          Ai3[g][kt] = ldA8(Wih3 + mrow*128 + kt*32 + q*8);
          Ah3[g][kt] = ldA8(Whh3 + mrow*128 + kt*32 + q*8);
        }
      }
      f16x8 aO[4]; float bo4[4] = {0,0,0,0};
      if (wid == 8){
        #pragma unroll
        for (int kt = 0; kt < 4; ++kt){
          f16x8 a;
          #pragma unroll
          for (int j = 0; j < 8; ++j)
            a[j] = (r < 4) ? (f16)Wout[r*128 + kt*32 + q*8 + j] : (f16)0.f;
          aO[kt] = a;
        }
        #pragma unroll
        for (int e = 0; e < 4; ++e) bo4[e] = bout[e];
      }
      float dhC = 0.f, dhN = dd[(size_t)(b0+r)*TT + 0];
      __syncthreads();

      for (int s = 0; s <= TT+1; ++s){
        const int par = s & 1;
        fragW_lds(sD + par*256, dG, r, hS);                   // raw h3(s-2) for head
        if (s >= 2 && s <= TT){
          #pragma unroll
          for (int e = 0; e < 4; ++e)
            hS[e] *= __expf(-fmaxf(dhC*WdhL[e] + bdhL[e], 0.f));
        }
        if (s >= 1 && s <= TT) fragW_lds(sC + par*256, dG, r, hS);  // decayed (own B-op)
        barrier_lds();
        if (s >= 1 && s <= TT){
          f16x8 bh4[4], bi3[4];
          #pragma unroll
          for (int kt = 0; kt < 4; ++kt) bh4[kt] = sC[par*256 + kt*64 + lane];
          #pragma unroll
          for (int kt = 0; kt < 4; ++kt) bi3[kt] = sB[par*256 + kt*64 + lane];
          f32x4v C0 = {0,0,0,0}, C1 = {0,0,0,0}, Ci2 = {0,0,0,0}, Ch2 = {0,0,0,0};
          #pragma unroll
          for (int kt = 0; kt < 4; ++kt) C0  = MFMA(Ah3[0][kt], bh4[kt], C0);
          #pragma unroll
          for (int kt = 0; kt < 4; ++kt) C1  = MFMA(Ah3[1][kt], bh4[kt], C1);
          #pragma unroll
          for (int kt = 0; kt < 4; ++kt) Ch2 = MFMA(Ah3[2][kt], bh4[kt], Ch2);
          #pragma unroll
          for (int kt = 0; kt < 4; ++kt) C0  = MFMA(Ai3[0][kt], bi3[kt], C0);
          #pragma unroll
          for (int kt = 0; kt < 4; ++kt) C1  = MFMA(Ai3[1][kt], bi3[kt], C1);
          #pragma unroll
          for (int kt = 0; kt < 4; ++kt) Ci2 = MFMA(Ai3[2][kt], bi3[kt], Ci2);
          gates_upd2(C0, C1, Ci2, Ch2, bR, bZ, bI, bH, hS);   // hS = h3(s-1)
        }
        if (s >= 2 && wid == 8){
          f32x4v cl = {0.f,0.f,0.f,0.f};
          #pragma unroll
          for (int kt = 0; kt < 4; ++kt) cl = MFMA(aO[kt], sD[par*256 + kt*64 + lane], cl);
          if (lane < 16){
            float l0 = cl[0]+bo4[0], l1 = cl[1]+bo4[1], l2 = cl[2]+bo4[2], l3 = cl[3]+bo4[3];
            float mx = fmaxf(fmaxf(l0,l1), fmaxf(l2,l3));
            float e0 = __expf(l0-mx), e1 = __expf(l1-mx), e2 = __expf(l2-mx), e3 = __expf(l3-mx);
            float inv = 1.f/(e0+e1+e2+e3);
            float4 o; o.x = e0*inv; o.y = e1*inv; o.z = e2*inv; o.w = e3*inv;
            *(float4*)(y + ((size_t)(b0+lane)*TT + (s-2))*4) = o;
          }
        }
        dhC = dhN;
        const int tn = s + 1;
        const int tp = (tn < TT) ? tn : (TT-1);
        dhN = dd[(size_t)(b0+r)*TT + tp];
      }
    }
  }
}

extern "C" void kernel_launch(void* const* d_in, const int* in_sizes, int n_in,
                              void* d_out, int out_size, void* d_ws, size_t ws_size,
                              hipStream_t stream) {
  (void)in_sizes; (void)n_in; (void)out_size; (void)ws_size;
  u32*  wsf = (u32*)d_ws;
  char* wsd = (char*)d_ws + 16384;
  k_init<<<dim3(16), dim3(256), 0, stream>>>(wsf);
  k_pipe<<<dim3(64), dim3(1024), 0, stream>>>(
      (const float*)d_in[0],  (const float*)d_in[1],  (const float*)d_in[2],
      (const float*)d_in[3],  (const float*)d_in[4],  (const float*)d_in[5],
      (const float*)d_in[6],  (const float*)d_in[7],  (const float*)d_in[8],  (const float*)d_in[9],
      (const float*)d_in[10], (const float*)d_in[11], (const float*)d_in[12], (const float*)d_in[13],
      (const float*)d_in[14], (const float*)d_in[15], (const float*)d_in[16], (const float*)d_in[17],
      (const float*)d_in[18], (const float*)d_in[19],
      (const float*)d_in[20], (const float*)d_in[21],
      (const float*)d_in[22], (const float*)d_in[23],
      (float*)d_out, wsf, wsd);
}

// Round 11
// 1175.448 us; speedup vs baseline: 2.3120x; 2.3120x over previous
//
#include <hip/hip_runtime.h>

#define TT 512
#define VV 64
#define RING 32   // window-8 protocol: flags/ACKs multiples of 8; band [9,25]; ring 32

typedef _Float16 f16;
typedef f16 f16x8 __attribute__((ext_vector_type(8)));
typedef f16 f16x4 __attribute__((ext_vector_type(4)));
typedef float f32x4v __attribute__((ext_vector_type(4)));
typedef unsigned long long u64;
typedef unsigned u32;

// address_space(1): mailbox atomics lower to global_* (vmcnt-only), never flat_*
typedef __attribute__((address_space(1))) unsigned gu32;
typedef __attribute__((address_space(1))) unsigned long long gu64;

#define MFMA(A_,B_,C_) __builtin_amdgcn_mfma_f32_16x16x32_f16((A_),(B_),(C_),0,0,0)
#define AT_LD32(p)   __hip_atomic_load((gu32*)(void*)(p), __ATOMIC_RELAXED, __HIP_MEMORY_SCOPE_AGENT)
#define AT_ST32(p,v) __hip_atomic_store((gu32*)(void*)(p),(v), __ATOMIC_RELAXED, __HIP_MEMORY_SCOPE_AGENT)
#define AT_LD64(p)   __hip_atomic_load((gu64*)(void*)(p), __ATOMIC_RELAXED, __HIP_MEMORY_SCOPE_AGENT)
#define AT_ST64(p,v) __hip_atomic_store((gu64*)(void*)(p),(v), __ATOMIC_RELAXED, __HIP_MEMORY_SCOPE_AGENT)

__device__ __forceinline__ void barrier_lds(){ asm volatile("s_waitcnt lgkmcnt(0)\n\ts_barrier" ::: "memory"); }
__device__ __forceinline__ void wait_vm0(){ asm volatile("s_waitcnt vmcnt(0)" ::: "memory"); }
__device__ __forceinline__ float4 ld4(const float* p){ return *(const float4*)p; }

__device__ __forceinline__ f16x8 ldA8(const float* p){
  f16x8 a;
  #pragma unroll
  for (int j = 0; j < 8; ++j) a[j] = (f16)p[j];
  return a;
}

// element offset (in f16 units) of (k=d0..d0+3, col=b) inside a B-frag buffer
// layout: [kt][lane'][j], lane' = ((d&31)>>3)*16 + b, j = d&7
__device__ __forceinline__ int fragOff16(int d0, int b){
  const int kt = d0 >> 5, qq = (d0 >> 3) & 3, j0 = d0 & 7;
  return (kt*64 + qq*16 + b)*8 + j0;
}

__device__ __forceinline__ void fragW_lds(f16x8* buf, int d0, int b, const float* h4){
  f16x4 v;
  #pragma unroll
  for (int e = 0; e < 4; ++e) v[e] = (f16)h4[e];
  *(f16x4*)((f16*)buf + fragOff16(d0, b)) = v;
}

__device__ __forceinline__ void pubFrag(char* slot, int d0, int b, const float* h4){
  union { f16x4 v; u64 u; } uu;
  #pragma unroll
  for (int e = 0; e < 4; ++e) uu.v[e] = (f16)h4[e];
  AT_ST64((u64*)(slot + fragOff16(d0, b)*2), uu.u);
}

__device__ __forceinline__ f16x8 impFrag(const char* slot, int kt, int lane){
  union { u64 u[2]; f16x8 v; } vv;
  const u64* p = (const u64*)(slot + (kt*64 + lane)*16);
  vv.u[0] = AT_LD64((u64*)p);
  vv.u[1] = AT_LD64((u64*)(p + 1));
  return vv.v;
}

__device__ __forceinline__ void spin_ge(u32* f, u32 val){
  if ((threadIdx.x & 63) == 0){
    u32 g = 0;
    while (AT_LD32(f) < val && ++g < (1u << 20)) {}
  }
  asm volatile("" ::: "memory");
}

// Fused-acc gates (R8): C0 = r-gate sum, C1 = z-gate sum; n needs Ci2/Ch2 separate.
__device__ __forceinline__ void gates_upd2(const f32x4v& C0, const f32x4v& C1,
                                           const f32x4v& Ci2, const f32x4v& Ch2,
                                           const float* bR, const float* bZ,
                                           const float* bI, const float* bH,
                                           float* hp){
  #pragma unroll
  for (int e = 0; e < 4; ++e){
    float rr = 1.f/(1.f + __expf(-(C0[e] + bR[e])));
    float zz = 1.f/(1.f + __expf(-(C1[e] + bZ[e])));
    float nv = Ci2[e] + bI[e] + rr*(Ch2[e] + bH[e]);
    float nn = 1.f - 2.f/(1.f + __expf(2.f*nv));
    hp[e] = (1.f - zz)*nn + zz*hp[e];
  }
}

__global__ void k_init(u32* wsf){
  const int i = blockIdx.x*256 + threadIdx.x;
  if (i < 4096) AT_ST32(wsf + i, 0u);
}

// R11 = R8 skeleton + chain cuts:
// (1) x-side MFMAs hoisted ABOVE the barrier: roles 1/2 use reg-resident bi +
//     stable LDS Wih; role 0 stages xi(t+1) at step t (double-buffered sX1) so
//     step t's x-MFMAs read last step's staging pre-barrier.
// (2) bi prefetch at step top (right after x-MFMAs = last use) -> full-step cover.
// (3) Window-8 + ring-32 + windowed ACKs. Consumer spin at s%8==7:
//     flag >= min(s+9,TT) (s+9 = mult of 8, exact). Producer gate at t%8==0,
//     t>=32: ACK >= t-24 (exact). Band [9,25]. Initial consumer spin: flag >= 8.
//     Alias: window writes slots t..t+7; consumer prefetch slot <= t-8 (>=8 apart);
//     overwrite of step t-32 needs ACK >= t-31 < t-24 gate. No per-step ACK stores.
__launch_bounds__(512, 1)
__global__ void k_pipe(const float* __restrict__ x,   const float* __restrict__ dd,
                       const float* __restrict__ m1,
                       const float* __restrict__ h01, const float* __restrict__ h02,
                       const float* __restrict__ h03,
                       const float* __restrict__ Wih1, const float* __restrict__ Whh1,
                       const float* __restrict__ bih1, const float* __restrict__ bhh1,
                       const float* __restrict__ Wih2, const float* __restrict__ Whh2,
                       const float* __restrict__ bih2, const float* __restrict__ bhh2,
                       const float* __restrict__ Wih3, const float* __restrict__ Whh3,
                       const float* __restrict__ bih3, const float* __restrict__ bhh3,
                       const float* __restrict__ Wout, const float* __restrict__ bout,
                       const float* __restrict__ Wdx,  const float* __restrict__ bdx,
                       const float* __restrict__ Wdh,  const float* __restrict__ bdh,
                       float* __restrict__ y, u32* __restrict__ wsf, char* __restrict__ wsd)
{
  __shared__ f16x8 sW[8*12*64];     // 96 KB: per-wave staged weight matrix (R8)
  __shared__ f16x8 sFrag[2][256];   // h B-frags (all 8 tiles)
  __shared__ f16x8 sX1[2][128];     // L1: x B-frags (double-buffered, staged 1 step early)
  __shared__ f16x8 sHead[2][256];   // L3: raw-h3 for delayed head

  const int tid = threadIdx.x, wid = tid >> 6, lane = tid & 63;
  const int q = lane >> 4, r = lane & 15;
  const int blk = blockIdx.x, role = blk >> 5, grp = blk & 31, b0 = grp << 4;

  u32* const fl0 = wsf + grp*16;
  u32* const ak0 = wsf + 1024 + grp*16;
  u32* const fl1 = wsf + (32+grp)*16;
  u32* const ak1 = wsf + 1024 + (32+grp)*16;
  char* const ring0 = wsd + (size_t)grp*RING*4096;
  char* const ring1 = wsd + (size_t)(32+grp)*RING*4096;

  const int dG = wid*16 + 4*q;
  const int wbase = wid*12;   // sW fragment base for this wave

  const float* bihX = (role == 0) ? bih1 : (role == 1) ? bih2 : bih3;
  const float* bhhX = (role == 0) ? bhh1 : (role == 1) ? bhh2 : bhh3;
  const float* h0X  = (role == 0) ? h01  : (role == 1) ? h02  : h03;

  float bR[4], bZ[4], bI[4], bH[4], hS[4], WdhL[4], bdhL[4];
  #pragma unroll
  for (int e = 0; e < 4; ++e){
    const int d = dG + e;
    bR[e] = bihX[d] + bhhX[d];
    bZ[e] = bihX[128+d] + bhhX[128+d];
    bI[e] = bihX[256+d];
    bH[e] = bhhX[256+d];
    WdhL[e] = Wdh[d]; bdhL[e] = bdh[d];
  }
  { float4 a = ld4(h0X + (size_t)(b0+r)*128 + dG); hS[0]=a.x; hS[1]=a.y; hS[2]=a.z; hS[3]=a.w; }
  float dhC = 0.f, dhN = dd[(size_t)(b0+r)*TT + 1];

  // ===================== role 0: L1 producer =====================
  if (role == 0){
    f16x8 Ai[3][2];                         // x-side weights in regs (24)
    #pragma unroll
    for (int g = 0; g < 3; ++g){
      const int mrow = (g*8 + wid)*16 + r;
      #pragma unroll
      for (int kt = 0; kt < 2; ++kt) Ai[g][kt] = ldA8(Wih1 + mrow*64 + kt*32 + q*8);
      #pragma unroll
      for (int kt = 0; kt < 4; ++kt)        // h-side weights staged to LDS
        sW[(wbase + g*4 + kt)*64 + lane] = ldA8(Whh1 + mrow*128 + kt*32 + q*8);
    }
    const int bx = (wid & 3)*4 + q, v0 = 4*r;
    float Wdx4[4] = {0,0,0,0}, bdx4[4] = {0,0,0,0};
    float4 xC = {0,0,0,0}, x0v = {0,0,0,0}, xN = {0,0,0,0}, mN = {0,0,0,0};
    float dxN = 0.f;
    if (wid < 4){
      #pragma unroll
      for (int e = 0; e < 4; ++e){ Wdx4[e] = Wdx[v0+e]; bdx4[e] = bdx[v0+e]; }
      xC  = ld4(x + ((size_t)(b0+bx)*TT + 0)*VV + v0);
      x0v = xC;
      xN  = ld4(x  + ((size_t)(b0+bx)*TT + 1)*VV + v0);
      mN  = ld4(m1 + ((size_t)(b0+bx)*TT + 1)*VV + v0);
      dxN = dd[(size_t)(b0+bx)*TT + 1];
      // prologue: stage xi(0) = x[0] into sX1[0]
      float xi0[4] = {xC.x, xC.y, xC.z, xC.w};
      fragW_lds(&sX1[0][0], v0, bx, xi0);
    }
    __syncthreads();

    for (int t = 0; t < TT; ++t){
      const int par = t & 1;
      if ((t & 7) == 0 && t >= 32) spin_ge(ak0, (u32)(t-24));
      // stage xi(t+1) into sX1[(t+1)&1] (inputs all resident: xN=x[t+1], xC=x[t])
      if (wid < 4 && t + 1 < TT){
        float xi[4];
        const float* xc = (const float*)&xN; const float* xp = (const float*)&xC;
        const float* x0e = (const float*)&x0v; const float* me = (const float*)&mN;
        #pragma unroll
        for (int e = 0; e < 4; ++e){
          float gx = __expf(-fmaxf(dxN*Wdx4[e] + bdx4[e], 0.f));
          xi[e] = (xp[e]*gx + (1.f-gx)*x0e[e])*(1.f-me[e]) + me[e]*xc[e];
        }
        fragW_lds(&sX1[(t+1)&1][0], v0, bx, xi);
      }
      // x-side MFMAs pre-barrier (sX1[par] staged last step, crossed last barrier)
      f32x4v C0 = {0,0,0,0}, C1 = {0,0,0,0}, Ci2 = {0,0,0,0}, Ch2 = {0,0,0,0};
      {
        f16x8 bx1[2];
        #pragma unroll
        for (int kt = 0; kt < 2; ++kt) bx1[kt] = sX1[par][kt*64 + lane];
        #pragma unroll
        for (int kt = 0; kt < 2; ++kt) C0  = MFMA(Ai[0][kt], bx1[kt], C0);
        #pragma unroll
        for (int kt = 0; kt < 2; ++kt) C1  = MFMA(Ai[1][kt], bx1[kt], C1);
        #pragma unroll
        for (int kt = 0; kt < 2; ++kt) Ci2 = MFMA(Ai[2][kt], bx1[kt], Ci2);
      }
      if (t >= 1){
        #pragma unroll
        for (int e = 0; e < 4; ++e)
          hS[e] *= __expf(-fmaxf(dhC*WdhL[e] + bdhL[e], 0.f));
      }
      fragW_lds(&sFrag[par][0], dG, r, hS);
      barrier_lds();
      f16x8 bh4[4];
      #pragma unroll
      for (int kt = 0; kt < 4; ++kt) bh4[kt] = sFrag[par][kt*64 + lane];
      #pragma unroll
      for (int kt = 0; kt < 4; ++kt) C0  = MFMA(sW[(wbase + 0*4 + kt)*64 + lane], bh4[kt], C0);
      #pragma unroll
      for (int kt = 0; kt < 4; ++kt) C1  = MFMA(sW[(wbase + 1*4 + kt)*64 + lane], bh4[kt], C1);
      #pragma unroll
      for (int kt = 0; kt < 4; ++kt) Ch2 = MFMA(sW[(wbase + 2*4 + kt)*64 + lane], bh4[kt], Ch2);
      gates_upd2(C0, C1, Ci2, Ch2, bR, bZ, bI, bH, hS);
      pubFrag(ring0 + (size_t)(t & (RING-1))*4096, dG, r, hS);
      if ((t & 7) == 7){
        wait_vm0();
        barrier_lds();
        if (tid == 0) AT_ST32(fl0, (u32)(t+1));
      }
      dhC = dhN;
      const int tp = (t+2 < TT) ? (t+2) : (TT-1);
      dhN = dd[(size_t)(b0+r)*TT + tp];
      if (wid < 4){
        xC = xN;
        xN  = ld4(x  + ((size_t)(b0+bx)*TT + tp)*VV + v0);
        mN  = ld4(m1 + ((size_t)(b0+bx)*TT + tp)*VV + v0);
        dxN = dd[(size_t)(b0+bx)*TT + tp];
      }
    }
    return;
  }

  // ===================== role 1: L2 (ch0 -> ch1) =====================
  if (role == 1){
    f16x8 Ah[3][4];                          // h-side weights in regs (48)
    #pragma unroll
    for (int g = 0; g < 3; ++g){
      const int mrow = (g*8 + wid)*16 + r;
      #pragma unroll
      for (int kt = 0; kt < 4; ++kt){
        sW[(wbase + g*4 + kt)*64 + lane] = ldA8(Wih2 + mrow*128 + kt*32 + q*8);  // x-side to LDS
        Ah[g][kt] = ldA8(Whh2 + mrow*128 + kt*32 + q*8);
      }
    }
    __syncthreads();

    spin_ge(fl0, 8u);
    f16x8 bi[4];
    #pragma unroll
    for (int kt = 0; kt < 4; ++kt) bi[kt] = impFrag(ring0, kt, lane);

    for (int t = 0; t < TT; ++t){
      const int par = t & 1;
      if ((t & 7) == 0 && t >= 32) spin_ge(ak1, (u32)(t-24));
      // x-side MFMAs pre-barrier (bi = slot t, prefetched last step)
      f32x4v C0 = {0,0,0,0}, C1 = {0,0,0,0}, Ci2 = {0,0,0,0}, Ch2 = {0,0,0,0};
      #pragma unroll
      for (int kt = 0; kt < 4; ++kt) C0  = MFMA(sW[(wbase + 0*4 + kt)*64 + lane], bi[kt], C0);
      #pragma unroll
      for (int kt = 0; kt < 4; ++kt) C1  = MFMA(sW[(wbase + 1*4 + kt)*64 + lane], bi[kt], C1);
      #pragma unroll
      for (int kt = 0; kt < 4; ++kt) Ci2 = MFMA(sW[(wbase + 2*4 + kt)*64 + lane], bi[kt], Ci2);
      // prefetch next slot (last use of bi was just above -> full-step cover)
      if (t + 1 < TT){
        const char* sIn = ring0 + (size_t)((t+1) & (RING-1))*4096;
        #pragma unroll
        for (int kt = 0; kt < 4; ++kt) bi[kt] = impFrag(sIn, kt, lane);
      }
      if (t >= 1){
        #pragma unroll
        for (int e = 0; e < 4; ++e)
          hS[e] *= __expf(-fmaxf(dhC*WdhL[e] + bdhL[e], 0.f));
      }
      fragW_lds(&sFrag[par][0], dG, r, hS);
      barrier_lds();
      f16x8 bh4[4];
      #pragma unroll
      for (int kt = 0; kt < 4; ++kt) bh4[kt] = sFrag[par][kt*64 + lane];
      #pragma unroll
      for (int kt = 0; kt < 4; ++kt) C0  = MFMA(Ah[0][kt], bh4[kt], C0);
      #pragma unroll
      for (int kt = 0; kt < 4; ++kt) C1  = MFMA(Ah[1][kt], bh4[kt], C1);
      #pragma unroll
      for (int kt = 0; kt < 4; ++kt) Ch2 = MFMA(Ah[2][kt], bh4[kt], Ch2);
      gates_upd2(C0, C1, Ci2, Ch2, bR, bZ, bI, bH, hS);
      pubFrag(ring1 + (size_t)(t & (RING-1))*4096, dG, r, hS);
      if ((t & 7) == 7){
        wait_vm0();
        barrier_lds();
        if (tid == 0){ AT_ST32(fl1, (u32)(t+1)); AT_ST32(ak0, (u32)(t+1)); }
        if (t < TT-1) spin_ge(fl0, (u32)(t+9 <= TT ? t+9 : TT));
      }
      dhC = dhN;
      const int tp = (t+2 < TT) ? (t+2) : (TT-1);
      dhN = dd[(size_t)(b0+r)*TT + tp];
    }
    return;
  }

  // ===================== role 2: L3 + head (ch1 -> y), single barrier =====================
  {
    f16x8 Ah[3][4];
    #pragma unroll
    for (int g = 0; g < 3; ++g){
      const int mrow = (g*8 + wid)*16 + r;
      #pragma unroll
      for (int kt = 0; kt < 4; ++kt){
        sW[(wbase + g*4 + kt)*64 + lane] = ldA8(Wih3 + mrow*128 + kt*32 + q*8);
        Ah[g][kt] = ldA8(Whh3 + mrow*128 + kt*32 + q*8);
      }
    }
    f16x8 aO[4]; float bo4[4] = {0,0,0,0};
    if (wid == 4){
      #pragma unroll
      for (int kt = 0; kt < 4; ++kt){
        f16x8 a;
        #pragma unroll
        for (int j = 0; j < 8; ++j)
          a[j] = (r < 4) ? (f16)Wout[r*128 + kt*32 + q*8 + j] : (f16)0.f;
        aO[kt] = a;
      }
      #pragma unroll
      for (int e = 0; e < 4; ++e) bo4[e] = bout[e];
    }
    __syncthreads();

    spin_ge(fl1, 8u);
    f16x8 bi[4];
    #pragma unroll
    for (int kt = 0; kt < 4; ++kt) bi[kt] = impFrag(ring1, kt, lane);

    // s in [0, TT]: GRU step s for s<TT; head(h3(s-1)) -> y(s-1) for s>=1
    for (int s = 0; s <= TT; ++s){
      const int par = s & 1;
      // stage RAW h3(s-1) for the delayed head (shares the single barrier)
      fragW_lds(&sHead[par][0], dG, r, hS);
      f32x4v C0 = {0,0,0,0}, C1 = {0,0,0,0}, Ci2 = {0,0,0,0}, Ch2 = {0,0,0,0};
      if (s < TT){
        // x-side MFMAs pre-barrier (bi = slot s, prefetched last step)
        #pragma unroll
        for (int kt = 0; kt < 4; ++kt) C0  = MFMA(sW[(wbase + 0*4 + kt)*64 + lane], bi[kt], C0);
        #pragma unroll
        for (int kt = 0; kt < 4; ++kt) C1  = MFMA(sW[(wbase + 1*4 + kt)*64 + lane], bi[kt], C1);
        #pragma unroll
        for (int kt = 0; kt < 4; ++kt) Ci2 = MFMA(sW[(wbase + 2*4 + kt)*64 + lane], bi[kt], Ci2);
        if (s + 1 < TT){
          const char* sIn = ring1 + (size_t)((s+1) & (RING-1))*4096;
          #pragma unroll
          for (int kt = 0; kt < 4; ++kt) bi[kt] = impFrag(sIn, kt, lane);
        }
        if (s >= 1){
          #pragma unroll
          for (int e = 0; e < 4; ++e)
            hS[e] *= __expf(-fmaxf(dhC*WdhL[e] + bdhL[e], 0.f));
        }
        fragW_lds(&sFrag[par][0], dG, r, hS);
      }
      barrier_lds();
      if (s < TT){
        f16x8 bh4[4];
        #pragma unroll
        for (int kt = 0; kt < 4; ++kt) bh4[kt] = sFrag[par][kt*64 + lane];
        #pragma unroll
        for (int kt = 0; kt < 4; ++kt) C0  = MFMA(Ah[0][kt], bh4[kt], C0);
        #pragma unroll
        for (int kt = 0; kt < 4; ++kt) C1  = MFMA(Ah[1][kt], bh4[kt], C1);
        #pragma unroll
        for (int kt = 0; kt < 4; ++kt) Ch2 = MFMA(Ah[2][kt], bh4[kt], Ch2);
        gates_upd2(C0, C1, Ci2, Ch2, bR, bZ, bI, bH, hS);
      }
      if (s >= 1 && wid == 4){
        f32x4v cl = {0.f,0.f,0.f,0.f};
        #pragma unroll
        for (int kt = 0; kt < 4; ++kt) cl = MFMA(aO[kt], sHead[par][kt*64 + lane], cl);
        if (lane < 16){
          float l0 = cl[0]+bo4[0], l1 = cl[1]+bo4[1], l2 = cl[2]+bo4[2], l3 = cl[3]+bo4[3];
          float mx = fmaxf(fmaxf(l0,l1), fmaxf(l2,l3));
          float e0 = __expf(l0-mx), e1 = __expf(l1-mx), e2 = __expf(l2-mx), e3 = __expf(l3-mx);
          float inv = 1.f/(e0+e1+e2+e3);
          float4 o; o.x = e0*inv; o.y = e1*inv; o.z = e2*inv; o.w = e3*inv;
          *(float4*)(y + ((size_t)(b0+lane)*TT + (s-1))*4) = o;
        }
      }
      if ((s & 7) == 7 && s < TT){
        if (tid == 0) AT_ST32(ak1, (u32)(s+1));
        if (s < TT-1) spin_ge(fl1, (u32)(s+9 <= TT ? s+9 : TT));
      }
      dhC = dhN;
      const int tp = (s+2 < TT) ? (s+2) : (TT-1);
      dhN = dd[(size_t)(b0+r)*TT + tp];
    }
  }
}

extern "C" void kernel_launch(void* const* d_in, const int* in_sizes, int n_in,
                              void* d_out, int out_size, void* d_ws, size_t ws_size,
                              hipStream_t stream) {
  (void)in_sizes; (void)n_in; (void)out_size; (void)ws_size;
  u32*  wsf = (u32*)d_ws;
  char* wsd = (char*)d_ws + 16384;
  k_init<<<dim3(16), dim3(256), 0, stream>>>(wsf);
  k_pipe<<<dim3(96), dim3(512), 0, stream>>>(
      (const float*)d_in[0],  (const float*)d_in[1],  (const float*)d_in[2],
      (const float*)d_in[3],  (const float*)d_in[4],  (const float*)d_in[5],
      (const float*)d_in[6],  (const float*)d_in[7],  (const float*)d_in[8],  (const float*)d_in[9],
      (const float*)d_in[10], (const float*)d_in[11], (const float*)d_in[12], (const float*)d_in[13],
      (const float*)d_in[14], (const float*)d_in[15], (const float*)d_in[16], (const float*)d_in[17],
      (const float*)d_in[18], (const float*)d_in[19],
      (const float*)d_in[20], (const float*)d_in[21],
      (const float*)d_in[22], (const float*)d_in[23],
      (float*)d_out, wsf, wsd);
}